// Round 1
// baseline (1294.838 us; speedup 1.0000x reference)
//
#include <hip/hip_runtime.h>
#include <hip/hip_bf16.h>

// Problem constants (reference: A=8, B=32768, S=128, AD=16, H=64, NH=4, D=16)
#define A_N 8
#define B_N 32768
#define S_N 128
#define AD_N 16
#define H_N 64
#define NH_N 4
#define D_N 16

#define NB 16                 // batches per block
#define BLOCK (A_N * NB)      // 128 threads: tid = a*16 + bl
// LDS row: [0..63]=E(sa_enc) | [64..127]=K (later 'other') | [128..191]=S then V | pad 2
// stride 194 bf16 = 97 dwords (odd -> conflict-free across lanes)
#define ROW_STRIDE 194

__global__ __launch_bounds__(BLOCK, 2)
void attention_critic_kernel(
    const float* __restrict__ states, const float* __restrict__ actions,
    const float* __restrict__ Ws, const float* __restrict__ bs,
    const float* __restrict__ We, const float* __restrict__ be,
    const float* __restrict__ Wk, const float* __restrict__ Wsel,
    const float* __restrict__ Wv, const float* __restrict__ bv,
    const float* __restrict__ W1, const float* __restrict__ b1,
    const float* __restrict__ W2, const float* __restrict__ b2,
    float* __restrict__ out)
{
    __shared__ __hip_bfloat16 lds[BLOCK][ROW_STRIDE];

    const int tid = threadIdx.x;
    const int a  = tid >> 4;          // agent 0..7
    const int bl = tid & 15;          // local batch 0..15
    const int b  = blockIdx.x * NB + bl;
    const long row = (long)a * B_N + b;
    const float* srow = states  + row * S_N;
    const float* arow = actions + row * AD_N;

    // ---- Phase 1: sa_enc (E) and s_enc (S), shared streaming of the states row ----
    float acc_e[H_N], acc_s[H_N];
    #pragma unroll
    for (int h = 0; h < H_N; ++h) { acc_e[h] = be[h]; acc_s[h] = bs[h]; }

    for (int k0 = 0; k0 < S_N; k0 += 4) {
        float4 x = *reinterpret_cast<const float4*>(srow + k0);
        #pragma unroll
        for (int h = 0; h < H_N; ++h) {
            acc_e[h] += x.x * We[(k0    ) * H_N + h] + x.y * We[(k0 + 1) * H_N + h]
                      + x.z * We[(k0 + 2) * H_N + h] + x.w * We[(k0 + 3) * H_N + h];
            acc_s[h] += x.x * Ws[(k0    ) * H_N + h] + x.y * Ws[(k0 + 1) * H_N + h]
                      + x.z * Ws[(k0 + 2) * H_N + h] + x.w * Ws[(k0 + 3) * H_N + h];
        }
    }
    for (int k0 = 0; k0 < AD_N; k0 += 4) {   // actions part feeds E only (MAX_ACTION=1)
        float4 x = *reinterpret_cast<const float4*>(arow + k0);
        #pragma unroll
        for (int h = 0; h < H_N; ++h) {
            acc_e[h] += x.x * We[(S_N + k0    ) * H_N + h] + x.y * We[(S_N + k0 + 1) * H_N + h]
                      + x.z * We[(S_N + k0 + 2) * H_N + h] + x.w * We[(S_N + k0 + 3) * H_N + h];
        }
    }
    #pragma unroll
    for (int h = 0; h < H_N; ++h) {
        lds[tid][h]       = __float2bfloat16(fmaxf(acc_e[h], 0.f));   // E
        lds[tid][128 + h] = __float2bfloat16(fmaxf(acc_s[h], 0.f));   // S (temp in V slot)
    }

    // ---- Phase 2: Sel = S @ Wsel (regs), K = E @ Wk, V = relu(E @ Wv + bv) -> LDS ----
    float sel[H_N];
    #pragma unroll
    for (int j = 0; j < H_N; ++j) sel[j] = 0.f;
    for (int h = 0; h < H_N; ++h) {
        float s = __bfloat162float(lds[tid][128 + h]);
        #pragma unroll
        for (int nd = 0; nd < H_N; ++nd)
            sel[nd] += s * Wsel[(nd >> 4) * (H_N * D_N) + h * D_N + (nd & 15)];
    }

    float tmp[H_N];
    #pragma unroll
    for (int j = 0; j < H_N; ++j) tmp[j] = 0.f;
    for (int h = 0; h < H_N; ++h) {
        float e = __bfloat162float(lds[tid][h]);
        #pragma unroll
        for (int nd = 0; nd < H_N; ++nd)
            tmp[nd] += e * Wk[(nd >> 4) * (H_N * D_N) + h * D_N + (nd & 15)];
    }
    #pragma unroll
    for (int nd = 0; nd < H_N; ++nd) lds[tid][64 + nd] = __float2bfloat16(tmp[nd]);  // K

    #pragma unroll
    for (int nd = 0; nd < H_N; ++nd) tmp[nd] = bv[nd];
    for (int h = 0; h < H_N; ++h) {
        float e = __bfloat162float(lds[tid][h]);
        #pragma unroll
        for (int nd = 0; nd < H_N; ++nd)
            tmp[nd] += e * Wv[(nd >> 4) * (H_N * D_N) + h * D_N + (nd & 15)];
    }
    #pragma unroll
    for (int nd = 0; nd < H_N; ++nd)
        lds[tid][128 + nd] = __float2bfloat16(fmaxf(tmp[nd], 0.f));                  // V
    __syncthreads();

    // ---- Phase 3: exclude-self attention over agents (8-wide softmax, per head) ----
    const float scale = 0.25f;   // 1/sqrt(D)
    float w[NH_N * A_N];
    #pragma unroll
    for (int n = 0; n < NH_N; ++n) {
        float logit[A_N];
        #pragma unroll
        for (int j = 0; j < A_N; ++j) {
            float acc = 0.f;
            #pragma unroll
            for (int d = 0; d < D_N; ++d)
                acc += sel[n * 16 + d] * __bfloat162float(lds[j * NB + bl][64 + n * 16 + d]);
            logit[j] = (j == a) ? -1e9f : acc * scale;
        }
        float m = logit[0];
        #pragma unroll
        for (int j = 1; j < A_N; ++j) m = fmaxf(m, logit[j]);
        float ssum = 0.f, e[A_N];
        #pragma unroll
        for (int j = 0; j < A_N; ++j) { e[j] = __expf(logit[j] - m); ssum += e[j]; }
        float inv = 1.f / ssum;
        #pragma unroll
        for (int j = 0; j < A_N; ++j) w[n * A_N + j] = e[j] * inv;
    }
    __syncthreads();   // all K-reads done before 'other' overwrites the K slot

    float other[H_N];
    #pragma unroll
    for (int nd = 0; nd < H_N; ++nd) other[nd] = 0.f;
    #pragma unroll
    for (int n = 0; n < NH_N; ++n)
        #pragma unroll
        for (int j = 0; j < A_N; ++j) {
            float wj = w[n * A_N + j];
            #pragma unroll
            for (int d = 0; d < D_N; ++d)
                other[n * 16 + d] += wj * __bfloat162float(lds[j * NB + bl][128 + n * 16 + d]);
        }
    #pragma unroll
    for (int nd = 0; nd < H_N; ++nd) lds[tid][64 + nd] = __float2bfloat16(other[nd]);
    // own-row write, own-row read below -> no barrier needed

    // ---- Phase 4: critic head: h = relu([E|other] @ W1 + b1); q = h @ W2 + b2 ----
    float hacc[H_N];
    #pragma unroll
    for (int h = 0; h < H_N; ++h) hacc[h] = b1[h];
    for (int i = 0; i < 2 * H_N; ++i) {
        float xi = __bfloat162float(lds[tid][i]);
        #pragma unroll
        for (int h = 0; h < H_N; ++h) hacc[h] += xi * W1[i * H_N + h];
    }
    float q = b2[0];
    #pragma unroll
    for (int h = 0; h < H_N; ++h) q += fmaxf(hacc[h], 0.f) * W2[h];
    out[row] = q;
}

extern "C" void kernel_launch(void* const* d_in, const int* in_sizes, int n_in,
                              void* d_out, int out_size, void* d_ws, size_t ws_size,
                              hipStream_t stream) {
    const float* states  = (const float*)d_in[0];
    const float* actions = (const float*)d_in[1];
    const float* Ws      = (const float*)d_in[2];
    const float* bs      = (const float*)d_in[3];
    const float* We      = (const float*)d_in[4];
    const float* be      = (const float*)d_in[5];
    const float* Wk      = (const float*)d_in[6];
    const float* Wsel    = (const float*)d_in[7];
    const float* Wv      = (const float*)d_in[8];
    const float* bv      = (const float*)d_in[9];
    const float* W1      = (const float*)d_in[10];
    const float* b1      = (const float*)d_in[11];
    const float* W2      = (const float*)d_in[12];
    const float* b2      = (const float*)d_in[13];
    float* out = (float*)d_out;

    dim3 grid(B_N / NB);   // 2048 blocks
    dim3 block(BLOCK);     // 128 threads
    attention_critic_kernel<<<grid, block, 0, stream>>>(
        states, actions, Ws, bs, We, be, Wk, Wsel, Wv, bv, W1, b1, W2, b2, out);
}

// Round 2
// 336.268 us; speedup vs baseline: 3.8506x; 3.8506x over previous
//
#include <hip/hip_runtime.h>
#include <hip/hip_bf16.h>

// A=8, B=32768, S=128, AD=16, H=64, NH=4, D=16
#define A_N 8
#define B_N 32768
#define S_N 128
#define AD_N 16
#define H_N 64

typedef __attribute__((ext_vector_type(8))) short short8;
typedef __attribute__((ext_vector_type(4))) float floatx4;

#define MFMA16(a, b, c) __builtin_amdgcn_mfma_f32_16x16x32_bf16(a, b, c, 0, 0, 0)

__device__ __forceinline__ short f2bf(float f) {
    __hip_bfloat16 h = __float2bfloat16(f);
    return *reinterpret_cast<short*>(&h);
}
__device__ __forceinline__ float bf2f(short s) {
    return __uint_as_float(((unsigned)(unsigned short)s) << 16);
}

// ---- weight prep: bf16, transposed to [n][k] so B-fragments are 16B loads ----
// layout in ws (shorts): WeT[64][160] @0 | WsT[64][128] @10240 | WkT[64][64] @18432
//                        WselT[64][64] @22528 | WvT[64][64] @26624 | W1T[64][128] @30720
#define W_TOTAL 38912
__global__ void prep_weights(const float* __restrict__ Ws, const float* __restrict__ We,
                             const float* __restrict__ Wk, const float* __restrict__ Wsel,
                             const float* __restrict__ Wv, const float* __restrict__ W1,
                             short* __restrict__ w) {
    int idx = blockIdx.x * 256 + threadIdx.x;
    if (idx >= W_TOTAL) return;
    float v;
    if (idx < 10240)      { int n = idx / 160, k = idx % 160; v = (k < 144) ? We[k * 64 + n] : 0.f; }
    else if (idx < 18432) { int i = idx - 10240; int n = i / 128, k = i % 128; v = Ws[k * 64 + n]; }
    else if (idx < 22528) { int i = idx - 18432; int c = i / 64, h = i % 64; v = Wk[(c >> 4) * 1024 + h * 16 + (c & 15)]; }
    else if (idx < 26624) { int i = idx - 22528; int c = i / 64, h = i % 64; v = Wsel[(c >> 4) * 1024 + h * 16 + (c & 15)]; }
    else if (idx < 30720) { int i = idx - 26624; int c = i / 64, h = i % 64; v = Wv[(c >> 4) * 1024 + h * 16 + (c & 15)]; }
    else                  { int i = idx - 30720; int n = i / 128, k = i % 128; v = W1[k * 64 + n]; }
    w[idx] = f2bf(v);
}

// ---- fused attention-critic, MFMA ----
#define SE 136   // E buffer stride (elems): [E(64) | other(64) | pad 8]; 272B rows, 16B-mult
#define ST 88    // Senc/Sel, K, V stride; 176B rows, 16B-mult, 2-way banks

__global__ __launch_bounds__(256, 3)
void attention_critic_mfma(
    const float* __restrict__ states, const float* __restrict__ actions,
    const float* __restrict__ bs, const float* __restrict__ be,
    const float* __restrict__ bv, const float* __restrict__ b1,
    const float* __restrict__ W2, const float* __restrict__ b2,
    const short* __restrict__ wts, float* __restrict__ out)
{
    __shared__ short Eb[64 * SE];   // cols 0..63: sa_enc ; cols 64..127: 'other'
    __shared__ short Tb[64 * ST];   // s_enc, later Sel
    __shared__ short Kb[64 * ST];
    __shared__ short Vb[64 * ST];

    const int tid  = threadIdx.x;
    const int wv   = tid >> 6;      // wave 0..3 = M-tile
    const int lane = tid & 63;
    const int lq   = lane >> 4;     // quad
    const int ln   = lane & 15;
    const int b0   = blockIdx.x * 8;

    const short* WeT   = wts;
    const short* WsT   = wts + 10240;
    const short* WkT   = wts + 18432;
    const short* WselT = wts + 22528;
    const short* WvT   = wts + 26624;
    const short* W1T   = wts + 30720;

    // local row r = a*8 + bl ; A-fragment row for this lane (m = ln)
    const int rA = wv * 16 + ln;
    const int aA = rA >> 3, blA = rA & 7;
    const float* srow = states  + ((long)aA * B_N + b0 + blA) * S_N;
    const float* arow = actions + ((long)aA * B_N + b0 + blA) * AD_N;

    const floatx4 z = {0.f, 0.f, 0.f, 0.f};

    // ================= Phase 1: E = relu(X@We+be), Senc = relu(states@Ws+bs) =========
    floatx4 accE[4] = {z, z, z, z};
    floatx4 accS[4] = {z, z, z, z};
    #pragma unroll
    for (int s = 0; s < 4; ++s) {
        const int kk = s * 32 + lq * 8;
        float4 x0 = *reinterpret_cast<const float4*>(srow + kk);
        float4 x1 = *reinterpret_cast<const float4*>(srow + kk + 4);
        short8 af;
        af[0] = f2bf(x0.x); af[1] = f2bf(x0.y); af[2] = f2bf(x0.z); af[3] = f2bf(x0.w);
        af[4] = f2bf(x1.x); af[5] = f2bf(x1.y); af[6] = f2bf(x1.z); af[7] = f2bf(x1.w);
        #pragma unroll
        for (int nt = 0; nt < 4; ++nt) {
            short8 bE = *reinterpret_cast<const short8*>(WeT + (nt * 16 + ln) * 160 + kk);
            short8 bS = *reinterpret_cast<const short8*>(WsT + (nt * 16 + ln) * 128 + kk);
            accE[nt] = MFMA16(af, bE, accE[nt]);
            accS[nt] = MFMA16(af, bS, accS[nt]);
        }
    }
    {   // tail k = 128..159 for E only: actions (k<144), zero pad (k>=144)
        const int kk = 128 + lq * 8;
        short8 af = {0, 0, 0, 0, 0, 0, 0, 0};
        if (lq < 2) {
            float4 x0 = *reinterpret_cast<const float4*>(arow + lq * 8);
            float4 x1 = *reinterpret_cast<const float4*>(arow + lq * 8 + 4);
            af[0] = f2bf(x0.x); af[1] = f2bf(x0.y); af[2] = f2bf(x0.z); af[3] = f2bf(x0.w);
            af[4] = f2bf(x1.x); af[5] = f2bf(x1.y); af[6] = f2bf(x1.z); af[7] = f2bf(x1.w);
        }
        #pragma unroll
        for (int nt = 0; nt < 4; ++nt) {
            short8 bE = *reinterpret_cast<const short8*>(WeT + (nt * 16 + ln) * 160 + kk);
            accE[nt] = MFMA16(af, bE, accE[nt]);
        }
    }
    // epilogue: C layout col = ln, row = lq*4 + i
    #pragma unroll
    for (int nt = 0; nt < 4; ++nt) {
        const int col = nt * 16 + ln;
        const float bE = be[col], bS = bs[col];
        #pragma unroll
        for (int i = 0; i < 4; ++i) {
            const int row = wv * 16 + lq * 4 + i;
            Eb[row * SE + col] = f2bf(fmaxf(accE[nt][i] + bE, 0.f));
            Tb[row * ST + col] = f2bf(fmaxf(accS[nt][i] + bS, 0.f));
        }
    }
    __syncthreads();

    // ================= Phase 2: Sel = Senc@Wsel ; K = E@Wk ; V = relu(E@Wv+bv) =======
    floatx4 accSel[4] = {z, z, z, z};
    #pragma unroll
    for (int s = 0; s < 2; ++s) {
        short8 af = *reinterpret_cast<const short8*>(Tb + rA * ST + s * 32 + lq * 8);
        #pragma unroll
        for (int nt = 0; nt < 4; ++nt)
            accSel[nt] = MFMA16(af, *reinterpret_cast<const short8*>(WselT + (nt * 16 + ln) * 64 + s * 32 + lq * 8), accSel[nt]);
    }
    floatx4 accK[4] = {z, z, z, z}, accV[4] = {z, z, z, z};
    #pragma unroll
    for (int s = 0; s < 2; ++s) {
        short8 af = *reinterpret_cast<const short8*>(Eb + rA * SE + s * 32 + lq * 8);
        #pragma unroll
        for (int nt = 0; nt < 4; ++nt) {
            accK[nt] = MFMA16(af, *reinterpret_cast<const short8*>(WkT + (nt * 16 + ln) * 64 + s * 32 + lq * 8), accK[nt]);
            accV[nt] = MFMA16(af, *reinterpret_cast<const short8*>(WvT + (nt * 16 + ln) * 64 + s * 32 + lq * 8), accV[nt]);
        }
    }
    #pragma unroll
    for (int nt = 0; nt < 4; ++nt) {
        const int col = nt * 16 + ln;
        const float bV = bv[col];
        #pragma unroll
        for (int i = 0; i < 4; ++i) {
            const int row = wv * 16 + lq * 4 + i;
            Kb[row * ST + col] = f2bf(accK[nt][i]);
            Vb[row * ST + col] = f2bf(fmaxf(accV[nt][i] + bV, 0.f));
        }
    }
    __syncthreads();   // all Tb (Senc) reads done; Kb/Vb visible
    #pragma unroll
    for (int nt = 0; nt < 4; ++nt)
        #pragma unroll
        for (int i = 0; i < 4; ++i)
            Tb[(wv * 16 + lq * 4 + i) * ST + nt * 16 + ln] = f2bf(accSel[nt][i]);
    __syncthreads();

    // ================= Phase 3: exclude-self attention (1 thread per row*head) =======
    {
        const int r3 = tid >> 2, hn = tid & 3;
        const int a3 = r3 >> 3, bl3 = r3 & 7;
        const int co = hn * 16;
        float selv[16];
        short8 s0 = *reinterpret_cast<const short8*>(Tb + r3 * ST + co);
        short8 s1 = *reinterpret_cast<const short8*>(Tb + r3 * ST + co + 8);
        #pragma unroll
        for (int d = 0; d < 8; ++d) { selv[d] = bf2f(s0[d]); selv[d + 8] = bf2f(s1[d]); }
        float lg[8];
        #pragma unroll
        for (int j = 0; j < 8; ++j) {
            const int rj = j * 8 + bl3;
            short8 k0 = *reinterpret_cast<const short8*>(Kb + rj * ST + co);
            short8 k1 = *reinterpret_cast<const short8*>(Kb + rj * ST + co + 8);
            float acc = 0.f;
            #pragma unroll
            for (int d = 0; d < 8; ++d) acc += selv[d] * bf2f(k0[d]) + selv[d + 8] * bf2f(k1[d]);
            lg[j] = (j == a3) ? -1e9f : acc * 0.25f;   // 1/sqrt(D)=0.25
        }
        float m = lg[0];
        #pragma unroll
        for (int j = 1; j < 8; ++j) m = fmaxf(m, lg[j]);
        float e[8], ssum = 0.f;
        #pragma unroll
        for (int j = 0; j < 8; ++j) { e[j] = __expf(lg[j] - m); ssum += e[j]; }
        const float inv = 1.f / ssum;
        float oth[16];
        #pragma unroll
        for (int d = 0; d < 16; ++d) oth[d] = 0.f;
        #pragma unroll
        for (int j = 0; j < 8; ++j) {
            const float wj = e[j] * inv;
            const int rj = j * 8 + bl3;
            short8 v0 = *reinterpret_cast<const short8*>(Vb + rj * ST + co);
            short8 v1 = *reinterpret_cast<const short8*>(Vb + rj * ST + co + 8);
            #pragma unroll
            for (int d = 0; d < 8; ++d) { oth[d] += wj * bf2f(v0[d]); oth[d + 8] += wj * bf2f(v1[d]); }
        }
        short8 o0, o1;
        #pragma unroll
        for (int d = 0; d < 8; ++d) { o0[d] = f2bf(oth[d]); o1[d] = f2bf(oth[d + 8]); }
        *reinterpret_cast<short8*>(Eb + r3 * SE + 64 + co)     = o0;
        *reinterpret_cast<short8*>(Eb + r3 * SE + 64 + co + 8) = o1;
    }
    __syncthreads();

    // ================= Phase 4: h = relu([E|other]@W1+b1) ; q = h@W2 + b2 ===========
    floatx4 accH[4] = {z, z, z, z};
    #pragma unroll
    for (int s = 0; s < 4; ++s) {
        short8 af = *reinterpret_cast<const short8*>(Eb + rA * SE + s * 32 + lq * 8);
        #pragma unroll
        for (int nt = 0; nt < 4; ++nt)
            accH[nt] = MFMA16(af, *reinterpret_cast<const short8*>(W1T + (nt * 16 + ln) * 128 + s * 32 + lq * 8), accH[nt]);
    }
    float p0 = 0.f, p1 = 0.f, p2 = 0.f, p3 = 0.f;
    #pragma unroll
    for (int nt = 0; nt < 4; ++nt) {
        const int col = nt * 16 + ln;
        const float w2v = W2[col], bb = b1[col];
        p0 += fmaxf(accH[nt][0] + bb, 0.f) * w2v;
        p1 += fmaxf(accH[nt][1] + bb, 0.f) * w2v;
        p2 += fmaxf(accH[nt][2] + bb, 0.f) * w2v;
        p3 += fmaxf(accH[nt][3] + bb, 0.f) * w2v;
    }
    #pragma unroll
    for (int mk = 1; mk < 16; mk <<= 1) {   // reduce across the 16 lanes of each quad-row group
        p0 += __shfl_xor(p0, mk, 64);
        p1 += __shfl_xor(p1, mk, 64);
        p2 += __shfl_xor(p2, mk, 64);
        p3 += __shfl_xor(p3, mk, 64);
    }
    if (ln == 0) {
        const float b2v = b2[0];
        float pr[4] = {p0, p1, p2, p3};
        #pragma unroll
        for (int i = 0; i < 4; ++i) {
            const int r = wv * 16 + lq * 4 + i;
            out[(long)(r >> 3) * B_N + b0 + (r & 7)] = pr[i] + b2v;
        }
    }
}

extern "C" void kernel_launch(void* const* d_in, const int* in_sizes, int n_in,
                              void* d_out, int out_size, void* d_ws, size_t ws_size,
                              hipStream_t stream) {
    const float* states  = (const float*)d_in[0];
    const float* actions = (const float*)d_in[1];
    const float* Ws      = (const float*)d_in[2];
    const float* bs      = (const float*)d_in[3];
    const float* We      = (const float*)d_in[4];
    const float* be      = (const float*)d_in[5];
    const float* Wk      = (const float*)d_in[6];
    const float* Wsel    = (const float*)d_in[7];
    const float* Wv      = (const float*)d_in[8];
    const float* bv      = (const float*)d_in[9];
    const float* W1      = (const float*)d_in[10];
    const float* b1      = (const float*)d_in[11];
    const float* W2      = (const float*)d_in[12];
    const float* b2      = (const float*)d_in[13];
    short* wts = (short*)d_ws;
    float* out = (float*)d_out;

    prep_weights<<<(W_TOTAL + 255) / 256, 256, 0, stream>>>(Ws, We, Wk, Wsel, Wv, W1, wts);
    attention_critic_mfma<<<B_N / 8, 256, 0, stream>>>(
        states, actions, bs, be, bv, b1, W2, b2, wts, out);
}